// Round 6
// baseline (171.383 us; speedup 1.0000x reference)
//
#include <hip/hip_runtime.h>
#include <hip/hip_bf16.h>
#include <string.h>

// GRU recommender via MFMA, R6: B=32768, T=64, H=16, launch vocab=3.
// One wave per block, FOUR independent 16-sample chains per wave (64 samples),
// 512 blocks. Model from R4/R5: wall = max(chain-latency L~930cyc, C*issue);
// R4 (2 waves x 1 chain) == R5 (1 wave x 2 chains) == 50us proves chains
// overlap and L dominates. C=4 concentrates 4 chains per SIMD -> ~2x.
//
// D[g][s] = W[g][:].h[:][s]: A = W_hh (static, RNE hi/lo split),
// B = h (RNE bf16 hi plane only). gx trick: A rows k=16..18 carry the 3-code
// gx LUT, k=19 carries L2*b_hh_n; B rows k=16..19 are a per-sample one-hot
// -> MFMA adds gx/bias itself, C-init is zero. A rows k>=20 zero kills the
// bpermute garbage in B there. Only the n-gate gx is applied in VALU (sel3).
//
// R6 new: whole 64-step launch_seq packed 2-bit -> 4 dwords per sample,
// distributed to chain owners via 16 setup bpermutes; in-loop code extraction
// is 2 shifts (no DS read). Loop body phase-ordered: 24 MFMAs (all chains),
// then gates, then packs + 16 batched bpermutes -> one lgkm drain point.

#define NBLK 512  // 32768 / 64 samples per wave

typedef __attribute__((ext_vector_type(8))) short    short8;
typedef __attribute__((ext_vector_type(4))) float    floatx4;
typedef __attribute__((ext_vector_type(4))) unsigned uintx4;

static __device__ __forceinline__ float fexp2(float x) { return __builtin_amdgcn_exp2f(x); }
static __device__ __forceinline__ float frcp(float x)  { return __builtin_amdgcn_rcpf(x); }
static __device__ __forceinline__ unsigned short bfrne(float f) {
    union { __hip_bfloat16 b; unsigned short u; } cv; cv.b = __float2bfloat16(f); return cv.u;
}
static __device__ __forceinline__ float bf2f(unsigned short u) {
    unsigned v = ((unsigned)u) << 16; float f; memcpy(&f, &v, 4); return f;
}
static __device__ __forceinline__ unsigned pkbf(float a, float b) {
    return (unsigned)bfrne(a) | ((unsigned)bfrne(b) << 16);
}
static __device__ __forceinline__ float sel3(int c, float a0, float a1, float a2) {
    return c == 0 ? a0 : (c == 1 ? a1 : a2);
}

__global__ __launch_bounds__(64) void gru_mfma(
    const int* __restrict__ user_id,
    const int* __restrict__ launch_seq,
    const float* __restrict__ user_emb,
    const float* __restrict__ launch_emb,
    const float* __restrict__ W_ih,
    const float* __restrict__ W_hh,
    const float* __restrict__ b_ih,
    const float* __restrict__ b_hh,
    const float* __restrict__ fc_W,
    const float* __restrict__ fc_b,
    float* __restrict__ out)
{
    constexpr float L  = 1.4426950408889634f;   // log2(e)
    constexpr float L2 = 2.8853900817779268f;   // 2*log2(e)

    __shared__ float gxlut[144];    // [(gate*3+code)*16 + dim]

    const int tid  = threadIdx.x;
    const int col  = tid & 15;
    const int quad = tid >> 4;
    const bool isq2 = (quad == 2);
    const long long sampBase = (long long)blockIdx.x * 64;

    // ---- pack own sample's 64 codes into 4 dwords (2 bits each) ----
    unsigned pk[4];
    {
        const int* sp = launch_seq + (sampBase + tid) * 64;
        #pragma unroll
        for (int w = 0; w < 4; ++w) {
            unsigned p = 0;
            #pragma unroll
            for (int j = 0; j < 4; ++j) {
                int4 v = ((const int4*)sp)[w * 4 + j];
                p |= ((unsigned)v.x & 3u) << (2 * (4 * j + 0));
                p |= ((unsigned)v.y & 3u) << (2 * (4 * j + 1));
                p |= ((unsigned)v.z & 3u) << (2 * (4 * j + 2));
                p |= ((unsigned)v.w & 3u) << (2 * (4 * j + 3));
            }
            pk[w] = p;
        }
    }

    // ---- gx LUT: 3 codes x 48 gates, pre-scaled ----
    for (int idx = tid; idx < 144; idx += 64) {
        int s = idx / 48, g = idx - s * 48;
        float dot = b_ih[g];
        #pragma unroll
        for (int k = 0; k < 16; ++k)
            dot = fmaf(W_ih[g * 16 + k], launch_emb[s * 16 + k], dot);
        int gate = g >> 4, dim = g & 15;
        gxlut[(gate * 3 + s) * 16 + dim] =
            (g < 32) ? (-L * (dot + b_hh[g])) : (L2 * dot);
    }

    // ---- redistribute seq words: chain c's codes = sample 16c+col ----
    unsigned sw[4][4];
    #pragma unroll
    for (int c = 0; c < 4; ++c) {
        int addr = (16 * c + col) * 4;
        #pragma unroll
        for (int w = 0; w < 4; ++w)
            sw[c][w] = (unsigned)__builtin_amdgcn_ds_bpermute(addr, (int)pk[w]);
    }

    __syncthreads();   // gxlut visible

    // ---- A fragments: W rows (quads 0,1), gx/bias rows (quad 2), zero (q3) ----
    short8 Wrh, Wrl, Wzh, Wzl, Wnh, Wnl;
    {
        auto makeW = [&](int goff, float scale, const float* gx3, float extra19,
                         short8& Hi, short8& Lo) {
            float w[8];
            #pragma unroll
            for (int j = 0; j < 8; ++j) w[j] = 0.f;
            if (quad < 2) {
                const float* row = W_hh + (goff + col) * 16 + quad * 8;
                #pragma unroll
                for (int j = 0; j < 8; ++j) w[j] = scale * row[j];
            } else if (quad == 2) {
                if (gx3) { w[0] = gx3[col]; w[1] = gx3[16 + col]; w[2] = gx3[32 + col]; }
                w[3] = extra19;
            }
            uintx4 hi, lo;
            #pragma unroll
            for (int p = 0; p < 4; ++p) {
                unsigned short h0 = bfrne(w[2 * p]), h1 = bfrne(w[2 * p + 1]);
                hi[p] = (unsigned)h0 | ((unsigned)h1 << 16);
                lo[p] = pkbf(w[2 * p] - bf2f(h0), w[2 * p + 1] - bf2f(h1));
            }
            Hi = __builtin_bit_cast(short8, hi);
            Lo = __builtin_bit_cast(short8, lo);
        };
        makeW(0,  -L, &gxlut[0],  0.f,                  Wrh, Wrl);
        makeW(16, -L, &gxlut[48], 0.f,                  Wzh, Wzl);
        makeW(32,  L2, (const float*)0, L2 * b_hh[32 + col], Wnh, Wnl);
    }

    // ---- per-lane gx_n LUT (n-gate gx added outside r*gh_n) ----
    floatx4 gn0 = *(const floatx4*)&gxlut[(6 + 0) * 16 + quad * 4];
    floatx4 gn1 = *(const floatx4*)&gxlut[(6 + 1) * 16 + quad * 4];
    floatx4 gn2 = *(const floatx4*)&gxlut[(6 + 2) * 16 + quad * 4];

    // bpermute source byte-addresses (loop-invariant, shared by all chains)
    const int a1 = (col + 32 * (quad & 1)) * 4;
    const int a2 = a1 + 64;

    // ---- chain state ----
    floatx4 h[4], pool[4];
    short8 B[4];
    #pragma unroll
    for (int c = 0; c < 4; ++c) {
        h[c] = floatx4{0.f, 0.f, 0.f, 0.f};
        pool[c] = floatx4{0.f, 0.f, 0.f, 0.f};
        unsigned c0 = sw[c][0] & 3u;
        unsigned P0 = (c0 == 0 ? 0x3F80u : 0u) | (c0 == 1 ? 0x3F800000u : 0u);
        unsigned P1 = (c0 == 2 ? 0x3F80u : 0u) | 0x3F800000u;
        uintx4 b = {isq2 ? P0 : 0u, isq2 ? P1 : 0u, 0u, 0u};
        B[c] = __builtin_bit_cast(short8, b);
    }

    const floatx4 CZ = {0.f, 0.f, 0.f, 0.f};

    for (int w = 0; w < 4; ++w) {
        unsigned cw[4], ncw[4];
        #pragma unroll
        for (int c = 0; c < 4; ++c) {
            cw[c]  = sw[c][w];
            ncw[c] = (sw[c][w] >> 2) | (w < 3 ? (sw[c][w + 1] << 30) : 0u);
        }
        #pragma unroll 4
        for (int tt = 0; tt < 16; ++tt) {
            // phase 1: all chains' MFMAs (consume B built last iteration)
            floatx4 accr[4], accz[4], accn[4];
            #pragma unroll
            for (int c = 0; c < 4; ++c) {
                accr[c] = __builtin_amdgcn_mfma_f32_16x16x32_bf16(Wrh, B[c], CZ, 0, 0, 0);
                accz[c] = __builtin_amdgcn_mfma_f32_16x16x32_bf16(Wzh, B[c], CZ, 0, 0, 0);
                accn[c] = __builtin_amdgcn_mfma_f32_16x16x32_bf16(Wnh, B[c], CZ, 0, 0, 0);
            }
            #pragma unroll
            for (int c = 0; c < 4; ++c) {
                accr[c] = __builtin_amdgcn_mfma_f32_16x16x32_bf16(Wrl, B[c], accr[c], 0, 0, 0);
                accz[c] = __builtin_amdgcn_mfma_f32_16x16x32_bf16(Wzl, B[c], accz[c], 0, 0, 0);
                accn[c] = __builtin_amdgcn_mfma_f32_16x16x32_bf16(Wnl, B[c], accn[c], 0, 0, 0);
            }
            // phase 2+3 per chain: gates, pack, one-hot, batched bpermutes
            #pragma unroll
            for (int c = 0; c < 4; ++c) {
                int cc = (int)(cw[c] & 3u);
                #pragma unroll
                for (int i = 0; i < 4; ++i) {
                    float gnv = sel3(cc, gn0[i], gn1[i], gn2[i]);
                    float r  = frcp(1.0f + fexp2(accr[c][i]));
                    float z  = frcp(1.0f + fexp2(accz[c][i]));
                    float y  = fmaf(r, accn[c][i], gnv);
                    float n  = fmaf(-2.0f, frcp(1.0f + fexp2(y)), 1.0f);
                    float hn = fmaf(z, h[c][i] - n, n);
                    h[c][i] = hn;
                    pool[c][i] += hn;
                }
                unsigned hp0 = pkbf(h[c][0], h[c][1]);
                unsigned hp1 = pkbf(h[c][2], h[c][3]);
                unsigned cn = ncw[c] & 3u;
                unsigned P0 = (cn == 0 ? 0x3F80u : 0u) | (cn == 1 ? 0x3F800000u : 0u);
                unsigned P1 = (cn == 2 ? 0x3F80u : 0u) | 0x3F800000u;
                uintx4 b;
                b[0] = (unsigned)__builtin_amdgcn_ds_bpermute(a1, (int)hp0);
                b[1] = (unsigned)__builtin_amdgcn_ds_bpermute(a1, (int)hp1);
                b[2] = (unsigned)__builtin_amdgcn_ds_bpermute(a2, (int)hp0);
                b[3] = (unsigned)__builtin_amdgcn_ds_bpermute(a2, (int)hp1);
                b[0] = isq2 ? P0 : b[0];   // one-hot rows k=16..19
                b[1] = isq2 ? P1 : b[1];
                B[c] = __builtin_bit_cast(short8, b);
                cw[c] >>= 2;
                ncw[c] >>= 2;
            }
        }
    }

    // ---- epilogue: FC over [u, mean(h)] for all 4 chains ----
    float4 fc1 = *(const float4*)&fc_W[quad * 4];
    float4 fc2 = *(const float4*)&fc_W[16 + quad * 4];
    const float inv64 = 1.0f / 64.0f;
    #pragma unroll
    for (int c = 0; c < 4; ++c) {
        long long s = sampBase + c * 16 + col;
        int uid = user_id[s];
        float4 u4 = *(const float4*)&user_emb[(long long)uid * 16 + quad * 4];
        float val = fc1.x * u4.x + fc1.y * u4.y + fc1.z * u4.z + fc1.w * u4.w;
        val = fmaf(fc2.x * inv64, pool[c][0], val);
        val = fmaf(fc2.y * inv64, pool[c][1], val);
        val = fmaf(fc2.z * inv64, pool[c][2], val);
        val = fmaf(fc2.w * inv64, pool[c][3], val);
        val += __shfl_xor(val, 16);
        val += __shfl_xor(val, 32);
        if (quad == 0) out[s] = val + fc_b[0];
    }
}

extern "C" void kernel_launch(void* const* d_in, const int* in_sizes, int n_in,
                              void* d_out, int out_size, void* d_ws, size_t ws_size,
                              hipStream_t stream) {
    const int*   user_id    = (const int*)d_in[0];
    const int*   launch_seq = (const int*)d_in[1];
    const float* user_emb   = (const float*)d_in[2];
    const float* launch_emb = (const float*)d_in[3];
    const float* W_ih       = (const float*)d_in[4];
    const float* W_hh       = (const float*)d_in[5];
    const float* b_ih       = (const float*)d_in[6];
    const float* b_hh       = (const float*)d_in[7];
    const float* fc_W       = (const float*)d_in[8];
    const float* fc_b       = (const float*)d_in[9];
    float* out = (float*)d_out;

    gru_mfma<<<dim3(NBLK), dim3(64), 0, stream>>>(
        user_id, launch_seq, user_emb, launch_emb,
        W_ih, W_hh, b_ih, b_hh, fc_W, fc_b, out);
}

// Round 7
// 134.228 us; speedup vs baseline: 1.2768x; 1.2768x over previous
//
#include <hip/hip_runtime.h>
#include <hip/hip_bf16.h>
#include <string.h>

// GRU recommender, R7: B=32768, T=64, H=16, vocab=3.
// 1024 blocks x 1 wave x 32 samples (sample = lane&31), 1 wave/SIMD on all
// 1024 SIMDs. Per step: 4x mfma_f32_32x32x16_bf16 and NO LDS/DS ops at all.
//
// MFMA1: rows [r(0..15); z(16..31)] = -L * W_hh[0:32] . h   (hi+lo A split)
// MFMA2: rows [n(0..15); zero]      = L2 * W_hh[32:48] . h  (hi+lo A split)
// C/D (m74/m101): col=lane&31=sample, row=(reg&3)+8*(reg>>2)+4*(lane>>5).
// A/B (std mapping): m/n=lane&31, k=8*(lane>>5)+j, j=0..7.
//
// DIM PERMUTATION trick: lane (n, half) receives D rows {0-3,8-11}+4*half,
// i.e. h-dims delta_j = 4*half + (j&3) + 8*(j>>2). Those are exactly its
// B-fragment k-slots k=8*half+j after permuting the hidden dimension by
// pi(k) = delta (applied consistently to W_hh rows+cols, b_hh, gx LUT, and
// fc_W's pooled half). So next step's B = 4 in-lane bf16 packs of this
// lane's own 8 h-values. The R4-R6 bpermute crossbar (the ~925cyc/step DS
// wall) disappears entirely.
//
// gx (vocab=3): per-lane VGPR LUT gxr/gxz/gxn[3][8] + 2-cndmask select.
// Numerics as R5 (absmax 7.8e-3): W RNE hi/lo split, h RNE bf16 hi only,
// sigmoid = rcp(1+exp2(-L*x)), tanh = 1-2*rcp(1+exp2(L2*x)).

#define NBLK 1024  // 32768 / 32 samples per wave

typedef __attribute__((ext_vector_type(8)))  short    short8;
typedef __attribute__((ext_vector_type(16))) float    floatx16;
typedef __attribute__((ext_vector_type(4)))  unsigned uintx4;

static __device__ __forceinline__ float fexp2(float x) { return __builtin_amdgcn_exp2f(x); }
static __device__ __forceinline__ float frcp(float x)  { return __builtin_amdgcn_rcpf(x); }
static __device__ __forceinline__ unsigned short bfrne(float f) {
    union { __hip_bfloat16 b; unsigned short u; } cv; cv.b = __float2bfloat16(f); return cv.u;
}
static __device__ __forceinline__ float bf2f(unsigned short u) {
    unsigned v = ((unsigned)u) << 16; float f; memcpy(&f, &v, 4); return f;
}
static __device__ __forceinline__ unsigned pkbf(float a, float b) {
    return (unsigned)bfrne(a) | ((unsigned)bfrne(b) << 16);
}
static __device__ __forceinline__ float sel3(int c, float a0, float a1, float a2) {
    return c == 0 ? a0 : (c == 1 ? a1 : a2);
}

__global__ __launch_bounds__(64) void gru_mfma32(
    const int* __restrict__ user_id,
    const int* __restrict__ launch_seq,
    const float* __restrict__ user_emb,
    const float* __restrict__ launch_emb,
    const float* __restrict__ W_ih,
    const float* __restrict__ W_hh,
    const float* __restrict__ b_ih,
    const float* __restrict__ b_hh,
    const float* __restrict__ fc_W,
    const float* __restrict__ fc_b,
    float* __restrict__ out)
{
    constexpr float L  = 1.4426950408889634f;   // log2(e)
    constexpr float L2 = 2.8853900817779268f;   // 2*log2(e)

    __shared__ float gxlut[144];    // [(gate*3+code)*16 + dim]

    const int tid  = threadIdx.x;
    const int n    = tid & 31;     // sample column
    const int half = tid >> 5;
    const int d1o  = 4 * half;     // this lane's dim blocks: [d1o..d1o+3], [d1o+8..d1o+11]
    const long long sampBase = (long long)blockIdx.x * 32;

    // ---- pack own sample's 64 codes into 4 dwords (2 bits each) ----
    unsigned pk[4];
    {
        const int* sp = launch_seq + (sampBase + n) * 64;
        #pragma unroll
        for (int w = 0; w < 4; ++w) {
            unsigned p = 0;
            #pragma unroll
            for (int j = 0; j < 4; ++j) {
                int4 v = ((const int4*)sp)[w * 4 + j];
                p |= ((unsigned)v.x & 3u) << (2 * (4 * j + 0));
                p |= ((unsigned)v.y & 3u) << (2 * (4 * j + 1));
                p |= ((unsigned)v.z & 3u) << (2 * (4 * j + 2));
                p |= ((unsigned)v.w & 3u) << (2 * (4 * j + 3));
            }
            pk[w] = p;
        }
    }

    // ---- gx LUT: 3 codes x 48 gates, pre-scaled ----
    for (int idx = tid; idx < 144; idx += 64) {
        int s = idx / 48, g = idx - s * 48;
        float dot = b_ih[g];
        #pragma unroll
        for (int k = 0; k < 16; ++k)
            dot = fmaf(W_ih[g * 16 + k], launch_emb[s * 16 + k], dot);
        int gate = g >> 4, dim = g & 15;
        gxlut[(gate * 3 + s) * 16 + dim] =
            (g < 32) ? (-L * (dot + b_hh[g])) : (L2 * dot);
    }

    // ---- A fragments (row m = n): rz stacked, n-gate; RNE hi/lo split ----
    // k-slot j of this lane = dim delta_j = d1o + (j&3) + 8*(j>>2)
    short8 Arzh, Arzl, Anh, Anl;
    {
        auto split8 = [&](const float* w, short8& Hi, short8& Lo) {
            uintx4 hi, lo;
            #pragma unroll
            for (int p = 0; p < 4; ++p) {
                unsigned short h0 = bfrne(w[2 * p]), h1 = bfrne(w[2 * p + 1]);
                hi[p] = (unsigned)h0 | ((unsigned)h1 << 16);
                lo[p] = pkbf(w[2 * p] - bf2f(h0), w[2 * p + 1] - bf2f(h1));
            }
            Hi = __builtin_bit_cast(short8, hi);
            Lo = __builtin_bit_cast(short8, lo);
        };
        float w[8];
        const float* rowrz = W_hh + n * 16;            // rows 0..31 = [r;z]
        float4 a = *(const float4*)(rowrz + d1o);
        float4 b = *(const float4*)(rowrz + d1o + 8);
        w[0] = -L * a.x; w[1] = -L * a.y; w[2] = -L * a.z; w[3] = -L * a.w;
        w[4] = -L * b.x; w[5] = -L * b.y; w[6] = -L * b.z; w[7] = -L * b.w;
        split8(w, Arzh, Arzl);
        if (n < 16) {
            const float* rown = W_hh + (32 + n) * 16;
            a = *(const float4*)(rown + d1o);
            b = *(const float4*)(rown + d1o + 8);
            w[0] = L2 * a.x; w[1] = L2 * a.y; w[2] = L2 * a.z; w[3] = L2 * a.w;
            w[4] = L2 * b.x; w[5] = L2 * b.y; w[6] = L2 * b.z; w[7] = L2 * b.w;
        } else {
            #pragma unroll
            for (int j = 0; j < 8; ++j) w[j] = 0.f;
        }
        split8(w, Anh, Anl);
    }

    // ---- n-gate bias for this lane's dims ----
    float biasn[8];
    {
        float4 a = *(const float4*)&b_hh[32 + d1o];
        float4 b = *(const float4*)&b_hh[32 + d1o + 8];
        biasn[0] = L2 * a.x; biasn[1] = L2 * a.y; biasn[2] = L2 * a.z; biasn[3] = L2 * a.w;
        biasn[4] = L2 * b.x; biasn[5] = L2 * b.y; biasn[6] = L2 * b.z; biasn[7] = L2 * b.w;
    }

    __syncthreads();   // gxlut visible

    // ---- per-lane gx LUT: 3 gates x 3 codes x my 8 dims (72 VGPRs) ----
    float gxr[3][8], gxz[3][8], gxn[3][8];
    #pragma unroll
    for (int c = 0; c < 3; ++c) {
        #pragma unroll
        for (int gbl = 0; gbl < 2; ++gbl) {
            int off = d1o + 8 * gbl;
            float4 r4 = *(const float4*)&gxlut[(0 * 3 + c) * 16 + off];
            float4 z4 = *(const float4*)&gxlut[(1 * 3 + c) * 16 + off];
            float4 n4 = *(const float4*)&gxlut[(2 * 3 + c) * 16 + off];
            gxr[c][4 * gbl + 0] = r4.x; gxr[c][4 * gbl + 1] = r4.y;
            gxr[c][4 * gbl + 2] = r4.z; gxr[c][4 * gbl + 3] = r4.w;
            gxz[c][4 * gbl + 0] = z4.x; gxz[c][4 * gbl + 1] = z4.y;
            gxz[c][4 * gbl + 2] = z4.z; gxz[c][4 * gbl + 3] = z4.w;
            gxn[c][4 * gbl + 0] = n4.x; gxn[c][4 * gbl + 1] = n4.y;
            gxn[c][4 * gbl + 2] = n4.z; gxn[c][4 * gbl + 3] = n4.w;
        }
    }

    // ---- recurrence: no DS ops, no barriers, pure VGPR + MFMA ----
    floatx16 CZ;
    #pragma unroll
    for (int i = 0; i < 16; ++i) CZ[i] = 0.f;

    float h[8], pool[8];
    #pragma unroll
    for (int j = 0; j < 8; ++j) { h[j] = 0.f; pool[j] = 0.f; }
    short8 B = {0, 0, 0, 0, 0, 0, 0, 0};   // h0 = 0

    #pragma unroll
    for (int w = 0; w < 4; ++w) {
        unsigned cw = pk[w];
        #pragma unroll
        for (int tt = 0; tt < 16; ++tt) {
            int c = (int)(cw & 3u);
            cw >>= 2;

            floatx16 drz = __builtin_amdgcn_mfma_f32_32x32x16_bf16(Arzh, B, CZ, 0, 0, 0);
            floatx16 dn  = __builtin_amdgcn_mfma_f32_32x32x16_bf16(Anh,  B, CZ, 0, 0, 0);
            drz = __builtin_amdgcn_mfma_f32_32x32x16_bf16(Arzl, B, drz, 0, 0, 0);
            dn  = __builtin_amdgcn_mfma_f32_32x32x16_bf16(Anl,  B, dn,  0, 0, 0);

            #pragma unroll
            for (int j = 0; j < 8; ++j) {
                float gr = sel3(c, gxr[0][j], gxr[1][j], gxr[2][j]);
                float gz = sel3(c, gxz[0][j], gxz[1][j], gxz[2][j]);
                float gn = sel3(c, gxn[0][j], gxn[1][j], gxn[2][j]);
                float r  = frcp(1.0f + fexp2(drz[j] + gr));
                float z  = frcp(1.0f + fexp2(drz[8 + j] + gz));
                float y  = fmaf(r, dn[j] + biasn[j], gn);
                float nn = fmaf(-2.0f, frcp(1.0f + fexp2(y)), 1.0f);
                h[j] = fmaf(z, h[j] - nn, nn);
                pool[j] += h[j];
            }
            uintx4 b;
            b[0] = pkbf(h[0], h[1]);
            b[1] = pkbf(h[2], h[3]);
            b[2] = pkbf(h[4], h[5]);
            b[3] = pkbf(h[6], h[7]);
            B = __builtin_bit_cast(short8, b);
        }
    }

    // ---- epilogue: FC over [u, mean(h)], half-split then xor-32 reduce ----
    float4 f1a = *(const float4*)&fc_W[d1o];
    float4 f1b = *(const float4*)&fc_W[d1o + 8];
    float4 f2a = *(const float4*)&fc_W[16 + d1o];
    float4 f2b = *(const float4*)&fc_W[16 + d1o + 8];
    int uid = user_id[sampBase + n];
    float4 ua = *(const float4*)&user_emb[(long long)uid * 16 + d1o];
    float4 ub = *(const float4*)&user_emb[(long long)uid * 16 + d1o + 8];
    const float inv64 = 1.0f / 64.0f;
    float val = f1a.x * ua.x + f1a.y * ua.y + f1a.z * ua.z + f1a.w * ua.w
              + f1b.x * ub.x + f1b.y * ub.y + f1b.z * ub.z + f1b.w * ub.w;
    val = fmaf(f2a.x * inv64, pool[0], val);
    val = fmaf(f2a.y * inv64, pool[1], val);
    val = fmaf(f2a.z * inv64, pool[2], val);
    val = fmaf(f2a.w * inv64, pool[3], val);
    val = fmaf(f2b.x * inv64, pool[4], val);
    val = fmaf(f2b.y * inv64, pool[5], val);
    val = fmaf(f2b.z * inv64, pool[6], val);
    val = fmaf(f2b.w * inv64, pool[7], val);
    val += __shfl_xor(val, 32);
    if (half == 0) out[sampBase + n] = val + fc_b[0];
}

extern "C" void kernel_launch(void* const* d_in, const int* in_sizes, int n_in,
                              void* d_out, int out_size, void* d_ws, size_t ws_size,
                              hipStream_t stream) {
    const int*   user_id    = (const int*)d_in[0];
    const int*   launch_seq = (const int*)d_in[1];
    const float* user_emb   = (const float*)d_in[2];
    const float* launch_emb = (const float*)d_in[3];
    const float* W_ih       = (const float*)d_in[4];
    const float* W_hh       = (const float*)d_in[5];
    const float* b_ih       = (const float*)d_in[6];
    const float* b_hh       = (const float*)d_in[7];
    const float* fc_W       = (const float*)d_in[8];
    const float* fc_b       = (const float*)d_in[9];
    float* out = (float*)d_out;

    gru_mfma32<<<dim3(NBLK), dim3(64), 0, stream>>>(
        user_id, launch_seq, user_emb, launch_emb,
        W_ih, W_hh, b_ih, b_hh, fc_W, fc_b, out);
}

// Round 8
// 126.630 us; speedup vs baseline: 1.3534x; 1.0600x over previous
//
#include <hip/hip_runtime.h>
#include <hip/hip_bf16.h>
#include <string.h>

// GRU recommender, R8: B=32768, T=64, H=16, vocab=3.
// 1024 blocks x 1 wave x 32 samples. No DS ops in the loop (R7 skeleton).
// R4/R5/R7 all measured ~57.7 cyc/sample-step => VALU-issue/stall bound;
// R8 cuts busy cycles:
//  - gx add for r/z moved into a 3rd MFMA: drz = Arz.B + Agx.B'
//    Agx K-slots 0..5 = gx table (3 codes, hi+lo bf16 => fp32-ish exact),
//    B' = per-sample one-hot rebuilt per step with 6 cndmask.
//  - n-gate bias folded into MFMA2's C operand (fp32).
//  - W bf16 RNE only (dropped lo plane): 2 weight MFMAs. Error budget:
//    ~same magnitude as h-hi-only quant, absmax ~1.5e-2 vs 5.4e-2 thr.
//  - h pack: bits+0x8000 round + v_perm (12 instr vs ~40 software-RNE).
// Layouts (verified by R7 passing): C/D col=lane&31, row=(reg&3)+8*(reg>>2)
// +4*(lane>>5); A/B m/n=lane&31, k=8*(lane>>5)+j. Hidden-dim permutation
// pi(8h+j)=4h+(j&3)+8*(j>>2) applied to W cols, b_hh, gxn, fc_W so each
// lane's 8 D-rows are exactly its 8 B k-slots (pure in-lane B rebuild).

#define NBLK 1024  // 32768 / 32 samples per wave

typedef __attribute__((ext_vector_type(8)))  short    short8;
typedef __attribute__((ext_vector_type(16))) float    floatx16;
typedef __attribute__((ext_vector_type(4)))  unsigned uintx4;

static __device__ __forceinline__ float fexp2(float x) { return __builtin_amdgcn_exp2f(x); }
static __device__ __forceinline__ float frcp(float x)  { return __builtin_amdgcn_rcpf(x); }
static __device__ __forceinline__ unsigned f2u(float f) { unsigned u; memcpy(&u, &f, 4); return u; }
static __device__ __forceinline__ unsigned short bfrne(float f) {
    union { __hip_bfloat16 b; unsigned short u; } cv; cv.b = __float2bfloat16(f); return cv.u;
}
static __device__ __forceinline__ float bf2f(unsigned short u) {
    unsigned v = ((unsigned)u) << 16; float f; memcpy(&f, &v, 4); return f;
}
// pack two floats as bf16 pair (a -> low16, b -> high16), round-half-up on bits
static __device__ __forceinline__ unsigned pkrnd(float a, float b) {
    unsigned ua = f2u(a) + 0x8000u;
    unsigned ub = f2u(b) + 0x8000u;
    return __builtin_amdgcn_perm(ub, ua, 0x07060302u);  // low16=ua.hi, high16=ub.hi
}
static __device__ __forceinline__ float sel3f(int c, float a0, float a1, float a2) {
    return c == 0 ? a0 : (c == 1 ? a1 : a2);
}
static __device__ __forceinline__ unsigned sel3u(int c, unsigned a0, unsigned a1, unsigned a2) {
    return c == 0 ? a0 : (c == 1 ? a1 : a2);
}

__global__ __launch_bounds__(64) void gru_mfma32(
    const int* __restrict__ user_id,
    const int* __restrict__ launch_seq,
    const float* __restrict__ user_emb,
    const float* __restrict__ launch_emb,
    const float* __restrict__ W_ih,
    const float* __restrict__ W_hh,
    const float* __restrict__ b_ih,
    const float* __restrict__ b_hh,
    const float* __restrict__ fc_W,
    const float* __restrict__ fc_b,
    float* __restrict__ out)
{
    constexpr float L  = 1.4426950408889634f;   // log2(e)
    constexpr float L2 = 2.8853900817779268f;   // 2*log2(e)

    __shared__ float gxlut[144];    // [(gate*3+code)*16 + dim]

    const int tid  = threadIdx.x;
    const int n    = tid & 31;     // sample column (and A row m)
    const int half = tid >> 5;
    const int d1o  = 4 * half;     // lane's dim blocks: [d1o..d1o+3], [d1o+8..d1o+11]
    const long long sampBase = (long long)blockIdx.x * 32;

    // ---- pack own sample's 64 codes into 4 dwords (2 bits each) ----
    unsigned pk[4];
    {
        const int* sp = launch_seq + (sampBase + n) * 64;
        #pragma unroll
        for (int w = 0; w < 4; ++w) {
            unsigned p = 0;
            #pragma unroll
            for (int j = 0; j < 4; ++j) {
                int4 v = ((const int4*)sp)[w * 4 + j];
                p |= ((unsigned)v.x & 3u) << (2 * (4 * j + 0));
                p |= ((unsigned)v.y & 3u) << (2 * (4 * j + 1));
                p |= ((unsigned)v.z & 3u) << (2 * (4 * j + 2));
                p |= ((unsigned)v.w & 3u) << (2 * (4 * j + 3));
            }
            pk[w] = p;
        }
    }

    // ---- gx LUT: 3 codes x 48 gates, pre-scaled ----
    for (int idx = tid; idx < 144; idx += 64) {
        int s = idx / 48, g = idx - s * 48;
        float dot = b_ih[g];
        #pragma unroll
        for (int k = 0; k < 16; ++k)
            dot = fmaf(W_ih[g * 16 + k], launch_emb[s * 16 + k], dot);
        int gate = g >> 4, dim = g & 15;
        gxlut[(gate * 3 + s) * 16 + dim] =
            (g < 32) ? (-L * (dot + b_hh[g])) : (L2 * dot);
    }

    // ---- weight A fragments (bf16 RNE, single plane) ----
    // k-slot j of this lane = dim pi = d1o + (j&3) + 8*(j>>2)
    short8 Arz, An;
    {
        auto pack8 = [&](const float* w) {
            uintx4 hi;
            #pragma unroll
            for (int p = 0; p < 4; ++p)
                hi[p] = (unsigned)bfrne(w[2 * p]) | ((unsigned)bfrne(w[2 * p + 1]) << 16);
            return __builtin_bit_cast(short8, hi);
        };
        float w[8];
        const float* rowrz = W_hh + n * 16;            // rows 0..31 = [r;z]
        float4 a = *(const float4*)(rowrz + d1o);
        float4 b = *(const float4*)(rowrz + d1o + 8);
        w[0] = -L * a.x; w[1] = -L * a.y; w[2] = -L * a.z; w[3] = -L * a.w;
        w[4] = -L * b.x; w[5] = -L * b.y; w[6] = -L * b.z; w[7] = -L * b.w;
        Arz = pack8(w);
        if (n < 16) {
            const float* rown = W_hh + (32 + n) * 16;
            a = *(const float4*)(rown + d1o);
            b = *(const float4*)(rown + d1o + 8);
            w[0] = L2 * a.x; w[1] = L2 * a.y; w[2] = L2 * a.z; w[3] = L2 * a.w;
            w[4] = L2 * b.x; w[5] = L2 * b.y; w[6] = L2 * b.z; w[7] = L2 * b.w;
        } else {
            #pragma unroll
            for (int j = 0; j < 8; ++j) w[j] = 0.f;
        }
        An = pack8(w);
    }

    __syncthreads();   // gxlut visible

    // ---- Agx fragment: K-slots 0..2 = gx hi (codes 0..2), 3..5 = gx lo ----
    // row m = n: m<16 -> r-gate dim m; m>=16 -> z-gate dim m-16. half==1 lanes zero.
    short8 Agx;
    {
        uintx4 d = {0u, 0u, 0u, 0u};
        if (half == 0) {
            const float* base = (n < 16) ? &gxlut[0] : &gxlut[48];
            int dim = n & 15;
            float g0 = base[0 * 16 + dim];
            float g1 = base[1 * 16 + dim];
            float g2 = base[2 * 16 + dim];
            unsigned short h0 = bfrne(g0), h1 = bfrne(g1), h2 = bfrne(g2);
            d[0] = (unsigned)h0 | ((unsigned)h1 << 16);
            d[1] = (unsigned)h2 | ((unsigned)bfrne(g0 - bf2f(h0)) << 16);
            d[2] = (unsigned)bfrne(g1 - bf2f(h1)) | ((unsigned)bfrne(g2 - bf2f(h2)) << 16);
        }
        Agx = __builtin_bit_cast(short8, d);
    }

    // ---- one-hot constants for B' (pre-masked by half) ----
    const unsigned khA = half ? 0u : 0x3F80u;        // bf16 1.0 in low16
    const unsigned khB = half ? 0u : 0x3F800000u;    // bf16 1.0 in high16

    // ---- n-gate C: bias in regs 0..7 (pi-dims), rest zero ----
    floatx16 Cn;
    #pragma unroll
    for (int i = 0; i < 16; ++i) Cn[i] = 0.f;
    {
        float4 a = *(const float4*)&b_hh[32 + d1o];
        float4 b = *(const float4*)&b_hh[32 + d1o + 8];
        Cn[0] = L2 * a.x; Cn[1] = L2 * a.y; Cn[2] = L2 * a.z; Cn[3] = L2 * a.w;
        Cn[4] = L2 * b.x; Cn[5] = L2 * b.y; Cn[6] = L2 * b.z; Cn[7] = L2 * b.w;
    }

    // ---- per-lane gx_n LUT (applied outside r*gh_n), pi-dims ----
    float gxn[3][8];
    #pragma unroll
    for (int c = 0; c < 3; ++c) {
        float4 a = *(const float4*)&gxlut[(6 + c) * 16 + d1o];
        float4 b = *(const float4*)&gxlut[(6 + c) * 16 + d1o + 8];
        gxn[c][0] = a.x; gxn[c][1] = a.y; gxn[c][2] = a.z; gxn[c][3] = a.w;
        gxn[c][4] = b.x; gxn[c][5] = b.y; gxn[c][6] = b.z; gxn[c][7] = b.w;
    }

    floatx16 CZ;
    #pragma unroll
    for (int i = 0; i < 16; ++i) CZ[i] = 0.f;

    float h[8], pool[8];
    #pragma unroll
    for (int j = 0; j < 8; ++j) { h[j] = 0.f; pool[j] = 0.f; }
    short8 B = {0, 0, 0, 0, 0, 0, 0, 0};   // h0 = 0

    // B' for t=0
    short8 Bp;
    {
        int c0 = (int)(pk[0] & 3u);
        uintx4 bp = { sel3u(c0, khA, khB, 0u),
                      sel3u(c0, khB, 0u, khA),
                      sel3u(c0, 0u, khA, khB), 0u };
        Bp = __builtin_bit_cast(short8, bp);
    }

    #pragma unroll
    for (int w = 0; w < 4; ++w) {
        unsigned cw  = pk[w];
        unsigned ncw = (pk[w] >> 2) | (w < 3 ? (pk[w + 1] << 30) : 0u);
        #pragma unroll
        for (int tt = 0; tt < 16; ++tt) {
            int c = (int)(cw & 3u);

            floatx16 t1  = __builtin_amdgcn_mfma_f32_32x32x16_bf16(Agx, Bp, CZ, 0, 0, 0);
            floatx16 dn  = __builtin_amdgcn_mfma_f32_32x32x16_bf16(An,  B, Cn, 0, 0, 0);
            floatx16 drz = __builtin_amdgcn_mfma_f32_32x32x16_bf16(Arz, B, t1, 0, 0, 0);

            #pragma unroll
            for (int j = 0; j < 8; ++j) {
                float gn = sel3f(c, gxn[0][j], gxn[1][j], gxn[2][j]);
                float r  = frcp(1.0f + fexp2(drz[j]));
                float z  = frcp(1.0f + fexp2(drz[8 + j]));
                float y  = fmaf(r, dn[j], gn);
                float nn = fmaf(-2.0f, frcp(1.0f + fexp2(y)), 1.0f);
                h[j] = fmaf(z, h[j] - nn, nn);
                pool[j] += h[j];
            }

            // next-step operands
            int cn = (int)(ncw & 3u);
            uintx4 bp = { sel3u(cn, khA, khB, 0u),
                          sel3u(cn, khB, 0u, khA),
                          sel3u(cn, 0u, khA, khB), 0u };
            Bp = __builtin_bit_cast(short8, bp);
            uintx4 b;
            b[0] = pkrnd(h[0], h[1]);
            b[1] = pkrnd(h[2], h[3]);
            b[2] = pkrnd(h[4], h[5]);
            b[3] = pkrnd(h[6], h[7]);
            B = __builtin_bit_cast(short8, b);
            cw >>= 2;
            ncw >>= 2;
        }
    }

    // ---- epilogue: FC over [u, mean(h)], pi-dims, xor-32 reduce ----
    float4 f1a = *(const float4*)&fc_W[d1o];
    float4 f1b = *(const float4*)&fc_W[d1o + 8];
    float4 f2a = *(const float4*)&fc_W[16 + d1o];
    float4 f2b = *(const float4*)&fc_W[16 + d1o + 8];
    int uid = user_id[sampBase + n];
    float4 ua = *(const float4*)&user_emb[(long long)uid * 16 + d1o];
    float4 ub = *(const float4*)&user_emb[(long long)uid * 16 + d1o + 8];
    const float inv64 = 1.0f / 64.0f;
    float val = f1a.x * ua.x + f1a.y * ua.y + f1a.z * ua.z + f1a.w * ua.w
              + f1b.x * ub.x + f1b.y * ub.y + f1b.z * ub.z + f1b.w * ub.w;
    val = fmaf(f2a.x * inv64, pool[0], val);
    val = fmaf(f2a.y * inv64, pool[1], val);
    val = fmaf(f2a.z * inv64, pool[2], val);
    val = fmaf(f2a.w * inv64, pool[3], val);
    val = fmaf(f2b.x * inv64, pool[4], val);
    val = fmaf(f2b.y * inv64, pool[5], val);
    val = fmaf(f2b.z * inv64, pool[6], val);
    val = fmaf(f2b.w * inv64, pool[7], val);
    val += __shfl_xor(val, 32);
    if (half == 0) out[sampBase + n] = val + fc_b[0];
}

extern "C" void kernel_launch(void* const* d_in, const int* in_sizes, int n_in,
                              void* d_out, int out_size, void* d_ws, size_t ws_size,
                              hipStream_t stream) {
    const int*   user_id    = (const int*)d_in[0];
    const int*   launch_seq = (const int*)d_in[1];
    const float* user_emb   = (const float*)d_in[2];
    const float* launch_emb = (const float*)d_in[3];
    const float* W_ih       = (const float*)d_in[4];
    const float* W_hh       = (const float*)d_in[5];
    const float* b_ih       = (const float*)d_in[6];
    const float* b_hh       = (const float*)d_in[7];
    const float* fc_W       = (const float*)d_in[8];
    const float* fc_b       = (const float*)d_in[9];
    float* out = (float*)d_out;

    gru_mfma32<<<dim3(NBLK), dim3(64), 0, stream>>>(
        user_id, launch_seq, user_emb, launch_emb,
        W_ih, W_hh, b_ih, b_hh, fc_W, fc_b, out);
}